// Round 1
// baseline (275.021 us; speedup 1.0000x reference)
//
#include <hip/hip_runtime.h>
#include <cmath>

#define NTOK 1024
#define HD   768
#define FF   3072
#define NE   8
#define NSLOT (NTOK * 2)
#define BK   64
#define CLD  130
#define NB_CONV 4608   // 16 matrices-halves * 288 tiles

typedef unsigned short u16;
typedef unsigned int   u32;
typedef __bf16 bf16x8 __attribute__((ext_vector_type(8)));
typedef float  f32x4  __attribute__((ext_vector_type(4)));
typedef u16    u16x8  __attribute__((ext_vector_type(8)));

__device__ __forceinline__ u16 f2bf(float f) {
  union { float f; u32 u; } v; v.f = f;
  u32 r = v.u + 0x7FFFu + ((v.u >> 16) & 1u);
  return (u16)(r >> 16);
}

// global->LDS direct DMA, 16B per lane. LDS dest wave-uniform base; HW writes
// base + lane*16. Global address is per-lane (gather OK).
__device__ __forceinline__ void load16(const void* g, void* l) {
  __builtin_amdgcn_global_load_lds(
      (const __attribute__((address_space(1))) u32*)g,
      (__attribute__((address_space(3))) u32*)l, 16, 0, 0);
}

// ---------------------------------------------------------------------------
// Fused kernel: blocks [0, NB_CONV) = weight convert+transpose,
// blocks [NB_CONV, NB_CONV+256) = router logits/top2 (independent work).
//
// Convert: fp32 [e][K][N] -> bf16 [e][N][K], 128k x 64n tile.
// Loads are register-clustered (all 8 float4 in flight -> one latency, not 8).
// Router path reads rw directly ([H][E] layout: 8 expert weights contiguous,
// L2-hot 24 KB) so smem is only the 16640 B convert tile -> 8 blocks/CU.
// ---------------------------------------------------------------------------
__global__ __launch_bounds__(256) void convert_router_kernel(
    const float* __restrict__ w1, const float* __restrict__ w2,
    u16* __restrict__ w1t, u16* __restrict__ w2t,
    const float* __restrict__ x, const float* __restrict__ rw,
    u16* __restrict__ xb, int* __restrict__ counts,
    int* __restrict__ ti, int* __restrict__ tpos, float* __restrict__ tg)
{
  __shared__ char smem[64 * CLD * 2];   // 16640 B
  const int tid  = threadIdx.x;
  const int lane = tid & 63;
  const int wid  = tid >> 6;

  if (blockIdx.x < NB_CONV) {
    // ---------------- convert path ----------------
    const int z   = blockIdx.x / 288;
    const int rem = blockIdx.x % 288;
    const float* src; u16* dst; int K, N, n0, k0;
    if (z < NE) {
      src = w1 + (size_t)z * HD * FF;  dst = w1t + (size_t)z * FF * HD;
      K = HD; N = FF;
      n0 = (rem % 48) * 64;  k0 = (rem / 48) * 128;
    } else {
      src = w2 + (size_t)(z - NE) * FF * HD;  dst = w2t + (size_t)(z - NE) * HD * FF;
      K = FF; N = HD;
      k0 = (rem % 24) * 128; n0 = (rem / 24) * 64;
    }
    u16* lt = (u16*)smem;             // [64 n][CLD k]
    const int rr = tid >> 4;          // k sub-row 0..15
    const int cc = (tid & 15) << 2;   // n 0..60

    // Phase 1: cluster all 8 loads (independent, no intervening uses).
    const float* s0 = src + (size_t)(k0 + rr) * N + n0 + cc;
    float4 v[8];
#pragma unroll
    for (int j = 0; j < 8; ++j) v[j] = *(const float4*)(s0 + (size_t)j * 16 * N);

    // Phase 2: convert + transpose into LDS.
#pragma unroll
    for (int j = 0; j < 8; ++j) {
      const int k = j * 16 + rr;
      lt[(cc + 0) * CLD + k] = f2bf(v[j].x); lt[(cc + 1) * CLD + k] = f2bf(v[j].y);
      lt[(cc + 2) * CLD + k] = f2bf(v[j].z); lt[(cc + 3) * CLD + k] = f2bf(v[j].w);
    }
    __syncthreads();

    // Phase 3: each store covers 4 FULL 256B row segments (no partial
    // sectors -> no fetch-on-write, single writeback per line).
    const int l15 = lane & 15;        // 16B chunk within row (k)
    const int r4  = lane >> 4;        // row within 4-row group
#pragma unroll
    for (int s = 0; s < 4; ++s) {
      const int r = wid * 16 + s * 4 + r4;   // n row 0..63
      u16x8 vv;
#pragma unroll
      for (int d = 0; d < 8; ++d) vv[d] = lt[r * CLD + l15 * 8 + d];
      *(u16x8*)(dst + (size_t)(n0 + r) * K + k0 + l15 * 8) = vv;
    }
  } else {
    // ---------------- router path (no LDS) ----------------
    const int t = (blockIdx.x - NB_CONV) * 4 + wid;
    const float* xrow = x + (size_t)t * HD;
    u16* xbrow = xb + (size_t)t * HD;

    float acc[NE] = {};
#pragma unroll
    for (int j = 0; j < 12; ++j) {
      const int h = lane + j * 64;
      const float xv = xrow[h];
      xbrow[h] = f2bf(xv);
      const float4 r0 = *(const float4*)(rw + h * 8);
      const float4 r1 = *(const float4*)(rw + h * 8 + 4);
      acc[0] += xv * r0.x; acc[1] += xv * r0.y;
      acc[2] += xv * r0.z; acc[3] += xv * r0.w;
      acc[4] += xv * r1.x; acc[5] += xv * r1.y;
      acc[6] += xv * r1.z; acc[7] += xv * r1.w;
    }
#pragma unroll
    for (int e = 0; e < NE; ++e) {
      float v = acc[e];
#pragma unroll
      for (int off = 32; off; off >>= 1) v += __shfl_down(v, off, 64);
      acc[e] = v;
    }

    if (lane == 0) {
      float v0 = -1e30f, v1 = -1e30f; int i0 = 0, i1 = 0;
#pragma unroll
      for (int e = 0; e < NE; ++e) {
        const float p = acc[e];
        if (p > v0) { v1 = v0; i1 = i0; v0 = p; i0 = e; }
        else if (p > v1) { v1 = p; i1 = e; }
      }
      const float e1 = expf(v1 - v0);
      const float g0 = 1.0f / (1.0f + e1);
      const float g1 = e1 / (1.0f + e1);
      const int p0 = atomicAdd(&counts[i0], 1);
      const int p1 = atomicAdd(&counts[i1], 1);
      ti[2 * t] = i0;  ti[2 * t + 1] = i1;
      tpos[2 * t] = p0; tpos[2 * t + 1] = p1;
      tg[2 * t] = g0;  tg[2 * t + 1] = g1;
    }
  }
}

// ---------------------------------------------------------------------------
// Router stage B: prefix-sum counts -> seg, scatter slots.
// ---------------------------------------------------------------------------
__global__ __launch_bounds__(1024) void router_scatter(
    const int* __restrict__ counts, const int* __restrict__ ti,
    const int* __restrict__ tpos, const float* __restrict__ tg,
    int* __restrict__ tos, float* __restrict__ gos, int* __restrict__ seg)
{
  __shared__ int offs[NE];
  const int t = threadIdx.x;
  if (t == 0) {
    int o = 0;
    for (int e = 0; e < NE; ++e) {
      offs[e] = o; seg[e] = o; seg[NE + e] = counts[e]; o += counts[e];
    }
  }
  __syncthreads();
  const int i0 = ti[2 * t], i1 = ti[2 * t + 1];
  const int s0 = offs[i0] + tpos[2 * t];
  const int s1 = offs[i1] + tpos[2 * t + 1];
  tos[s0] = t; gos[s0] = tg[2 * t];
  tos[s1] = t; gos[s1] = tg[2 * t + 1];
}

// ---------------------------------------------------------------------------
// FFN GEMM core: 128m x 64n tile, BK=64, 4 waves (2x2 over 64x32 each,
// acc 4x2). global_load_lds staging (A:4 + B:2 issues/wave), XOR-swizzled
// unpadded LDS (physical 16B chunk = logical ^ (row&7)).
// T3-minimum pipeline: double-buffered LDS, STAGE(next) issued BEFORE the
// MFMA phase on current -> stage latency hides under ds_read+MFMA; single
// __syncthreads per K-step (compiler emits the vmcnt(0) drain).
// ---------------------------------------------------------------------------

// FFN1: h = gelu(x_gather @ w1t[e]) -> hbuf (bf16)
__global__ __launch_bounds__(256) void ffn1_kernel(
    const u16* __restrict__ xb, const u16* __restrict__ w1t,
    const int* __restrict__ tos, const int* __restrict__ seg,
    u16* __restrict__ hbuf)
{
  const int e   = blockIdx.z;
  const int cnt = seg[NE + e];
  const int m0  = blockIdx.y * 128;
  if (m0 >= cnt) return;
  const int start = seg[e];
  const int n0    = blockIdx.x * 64;

  __shared__ __align__(16) u16 As[2][128 * 64];
  __shared__ __align__(16) u16 Bs[2][64 * 64];
  __shared__ int toks[128];

  const int tid = threadIdx.x;
  if (tid < 128) toks[tid] = tos[start + min(m0 + tid, cnt - 1)];
  __syncthreads();

  const int lane = tid & 63;
  const int wid  = tid >> 6;
  const int rsub = lane >> 3;           // 0..7
  const int c8   = (lane & 7) ^ rsub;   // logical 16B chunk

  const u16* ag[4]; int ao[4];
#pragma unroll
  for (int i = 0; i < 4; ++i) {
    const int rb = wid * 8 + i * 32;
    ag[i] = xb + (size_t)toks[rb + rsub] * HD + c8 * 8;
    ao[i] = rb * 64;
  }
  const u16* bg[2]; int bo[2];
#pragma unroll
  for (int i = 0; i < 2; ++i) {
    const int rb = wid * 8 + i * 32;
    bg[i] = w1t + ((size_t)e * FF + n0 + rb + rsub) * HD + c8 * 8;
    bo[i] = rb * 64;
  }

  const int wm  = (wid >> 1) << 6;      // 0 / 64
  const int wn  = (wid & 1) << 5;       // 0 / 32
  const int q   = lane >> 4;
  const int r16 = lane & 15;

  f32x4 acc[4][2] = {};

  // prologue: stage buf 0
#pragma unroll
  for (int i = 0; i < 4; ++i) load16(ag[i], &As[0][ao[i]]);
#pragma unroll
  for (int i = 0; i < 2; ++i) load16(bg[i], &Bs[0][bo[i]]);
  __syncthreads();

  int cur = 0;
  for (int k0 = 0; k0 < HD; k0 += BK) {
    const int nxt = cur ^ 1;
    if (k0 + BK < HD) {
#pragma unroll
      for (int i = 0; i < 4; ++i) load16(ag[i] + k0 + BK, &As[nxt][ao[i]]);
#pragma unroll
      for (int i = 0; i < 2; ++i) load16(bg[i] + k0 + BK, &Bs[nxt][bo[i]]);
    }
#pragma unroll
    for (int s = 0; s < 2; ++s) {
      const int pa = ((s << 2) + q) ^ (r16 & 7);
      bf16x8 af[4], bf[2];
#pragma unroll
      for (int t = 0; t < 4; ++t)
        af[t] = *(const bf16x8*)(&As[cur][(wm + t * 16 + r16) * 64 + pa * 8]);
#pragma unroll
      for (int t = 0; t < 2; ++t)
        bf[t] = *(const bf16x8*)(&Bs[cur][(wn + t * 16 + r16) * 64 + pa * 8]);
#pragma unroll
      for (int t = 0; t < 4; ++t)
#pragma unroll
        for (int c = 0; c < 2; ++c)
          acc[t][c] = __builtin_amdgcn_mfma_f32_16x16x32_bf16(af[t], bf[c], acc[t][c], 0, 0, 0);
    }
    __syncthreads();
    cur = nxt;
  }

#pragma unroll
  for (int t = 0; t < 4; ++t) {
    const int mbase = m0 + wm + t * 16 + q * 4;
#pragma unroll
    for (int i = 0; i < 4; ++i) {
      if (mbase + i < cnt) {
        u16* drow = hbuf + (size_t)(start + mbase + i) * FF + n0 + wn;
#pragma unroll
        for (int c = 0; c < 2; ++c) {
          float v = acc[t][c][i];
          v = 0.5f * v * (1.0f + erff(v * 0.70710678118f));
          drow[c * 16 + r16] = f2bf(v);
        }
      }
    }
  }
}

// FFN2: out += gate * (h @ w2t[e]), K-split x4, atomic fp32 accumulate.
#define KSPLIT 4
#define KSEG   (FF / KSPLIT)   // 768

__global__ __launch_bounds__(256) void ffn2_kernel(
    const u16* __restrict__ hbuf, const u16* __restrict__ w2t,
    const int* __restrict__ tos, const float* __restrict__ gos,
    const int* __restrict__ seg, float* __restrict__ out)
{
  const int ez  = blockIdx.z;
  const int e   = ez >> 2;
  const int ks  = ez & 3;
  const int cnt = seg[NE + e];
  const int m0  = blockIdx.y * 128;
  if (m0 >= cnt) return;
  const int start = seg[e];
  const int n0    = blockIdx.x * 64;
  const int kbase = ks * KSEG;

  __shared__ __align__(16) u16 As[2][128 * 64];
  __shared__ __align__(16) u16 Bs[2][64 * 64];
  __shared__ int   toks[128];
  __shared__ float gates[128];

  const int tid = threadIdx.x;
  if (tid < 128) {
    const int idx = start + min(m0 + tid, cnt - 1);
    toks[tid]  = tos[idx];
    gates[tid] = gos[idx];
  }
  __syncthreads();

  const int lane = tid & 63;
  const int wid  = tid >> 6;
  const int rsub = lane >> 3;
  const int c8   = (lane & 7) ^ rsub;

  const u16* ag[4]; int ao[4];
#pragma unroll
  for (int i = 0; i < 4; ++i) {
    const int rb = wid * 8 + i * 32;
    ag[i] = hbuf + (size_t)(start + min(m0 + rb + rsub, cnt - 1)) * FF + kbase + c8 * 8;
    ao[i] = rb * 64;
  }
  const u16* bg[2]; int bo[2];
#pragma unroll
  for (int i = 0; i < 2; ++i) {
    const int rb = wid * 8 + i * 32;
    bg[i] = w2t + ((size_t)e * HD + n0 + rb + rsub) * FF + kbase + c8 * 8;
    bo[i] = rb * 64;
  }

  const int wm  = (wid >> 1) << 6;
  const int wn  = (wid & 1) << 5;
  const int q   = lane >> 4;
  const int r16 = lane & 15;

  f32x4 acc[4][2] = {};

  // prologue: stage buf 0
#pragma unroll
  for (int i = 0; i < 4; ++i) load16(ag[i], &As[0][ao[i]]);
#pragma unroll
  for (int i = 0; i < 2; ++i) load16(bg[i], &Bs[0][bo[i]]);
  __syncthreads();

  int cur = 0;
  for (int k0 = 0; k0 < KSEG; k0 += BK) {
    const int nxt = cur ^ 1;
    if (k0 + BK < KSEG) {
#pragma unroll
      for (int i = 0; i < 4; ++i) load16(ag[i] + k0 + BK, &As[nxt][ao[i]]);
#pragma unroll
      for (int i = 0; i < 2; ++i) load16(bg[i] + k0 + BK, &Bs[nxt][bo[i]]);
    }
#pragma unroll
    for (int s = 0; s < 2; ++s) {
      const int pa = ((s << 2) + q) ^ (r16 & 7);
      bf16x8 af[4], bf[2];
#pragma unroll
      for (int t = 0; t < 4; ++t)
        af[t] = *(const bf16x8*)(&As[cur][(wm + t * 16 + r16) * 64 + pa * 8]);
#pragma unroll
      for (int t = 0; t < 2; ++t)
        bf[t] = *(const bf16x8*)(&Bs[cur][(wn + t * 16 + r16) * 64 + pa * 8]);
#pragma unroll
      for (int t = 0; t < 4; ++t)
#pragma unroll
        for (int c = 0; c < 2; ++c)
          acc[t][c] = __builtin_amdgcn_mfma_f32_16x16x32_bf16(af[t], bf[c], acc[t][c], 0, 0, 0);
    }
    __syncthreads();
    cur = nxt;
  }

#pragma unroll
  for (int t = 0; t < 4; ++t) {
    const int mbase = wm + t * 16 + q * 4;
#pragma unroll
    for (int i = 0; i < 4; ++i) {
      const int mloc = mbase + i;
      if (m0 + mloc < cnt) {
        const int tok  = toks[mloc];
        const float g  = gates[mloc];
        float* drow = out + (size_t)tok * HD + n0 + wn;
#pragma unroll
        for (int c = 0; c < 2; ++c) {
          atomicAdd(drow + c * 16 + r16, g * acc[t][c][i]);
        }
      }
    }
  }
}

// ---------------------------------------------------------------------------
extern "C" void kernel_launch(void* const* d_in, const int* in_sizes, int n_in,
                              void* d_out, int out_size, void* d_ws, size_t ws_size,
                              hipStream_t stream) {
  const float* x  = (const float*)d_in[0];
  const float* rw = (const float*)d_in[1];
  const float* w1 = (const float*)d_in[2];
  const float* w2 = (const float*)d_in[3];
  float* out = (float*)d_out;

  char* ws = (char*)d_ws;
  const size_t o_xb    = 0;
  const size_t o_hbuf  = o_xb + (size_t)NTOK * HD * 2;
  const size_t o_tos   = o_hbuf + (size_t)NSLOT * FF * 2;
  const size_t o_gos   = o_tos + (size_t)NSLOT * 4;
  const size_t o_seg   = o_gos + (size_t)NSLOT * 4;
  const size_t o_cnt   = o_seg + 64 * 4;
  const size_t o_ti    = o_cnt + NE * 4;
  const size_t o_tpos  = o_ti + (size_t)NSLOT * 4;
  const size_t o_tg    = o_tpos + (size_t)NSLOT * 4;
  const size_t o_w1t   = (o_tg + (size_t)NSLOT * 4 + 255) & ~(size_t)255;
  const size_t o_w2t   = o_w1t + (size_t)NE * HD * FF * 2;
  u16*   xb    = (u16*)(ws + o_xb);
  u16*   hbuf  = (u16*)(ws + o_hbuf);
  int*   tos   = (int*)(ws + o_tos);
  float* gos   = (float*)(ws + o_gos);
  int*   seg   = (int*)(ws + o_seg);
  int*   cnts  = (int*)(ws + o_cnt);
  int*   ti    = (int*)(ws + o_ti);
  int*   tpos  = (int*)(ws + o_tpos);
  float* tg    = (float*)(ws + o_tg);
  u16*   w1t   = (u16*)(ws + o_w1t);
  u16*   w2t   = (u16*)(ws + o_w2t);

  hipMemsetAsync(d_out, 0, (size_t)NTOK * HD * sizeof(float), stream);
  hipMemsetAsync(cnts, 0, NE * sizeof(int), stream);
  hipLaunchKernelGGL(convert_router_kernel, dim3(NB_CONV + NTOK / 4), dim3(256), 0, stream,
                     w1, w2, w1t, w2t, x, rw, xb, cnts, ti, tpos, tg);
  hipLaunchKernelGGL(router_scatter, dim3(1), dim3(1024), 0, stream,
                     cnts, ti, tpos, tg, tos, gos, seg);
  hipLaunchKernelGGL(ffn1_kernel, dim3(FF / 64, NTOK / 128, NE), dim3(256), 0, stream,
                     xb, w1t, tos, seg, hbuf);
  hipLaunchKernelGGL(ffn2_kernel, dim3(HD / 64, NTOK / 128, NE * KSPLIT), dim3(256), 0, stream,
                     hbuf, w2t, tos, gos, seg, out);
}

// Round 2
// 273.398 us; speedup vs baseline: 1.0059x; 1.0059x over previous
//
#include <hip/hip_runtime.h>
#include <cmath>

#define NTOK 1024
#define HD   768
#define FF   3072
#define NE   8
#define NSLOT (NTOK * 2)
#define BK   64
#define CLD  130

#define NB_ROUTER 256          // 4 tokens per block
#define NB_CONV1  2304         // 8 experts * 288 tiles (w1)
#define NB_CONV2  2304         // 8 experts * 288 tiles (w2)
#define NB_FFN1   3072         // 48 n * 8 m * 8 e

typedef unsigned short u16;
typedef unsigned int   u32;
typedef __bf16 bf16x8 __attribute__((ext_vector_type(8)));
typedef float  f32x4  __attribute__((ext_vector_type(4)));
typedef u16    u16x8  __attribute__((ext_vector_type(8)));

__device__ __forceinline__ u16 f2bf(float f) {
  union { float f; u32 u; } v; v.f = f;
  u32 r = v.u + 0x7FFFu + ((v.u >> 16) & 1u);
  return (u16)(r >> 16);
}

// global->LDS direct DMA, 16B per lane. LDS dest wave-uniform base; HW writes
// base + lane*16. Global address is per-lane (gather OK).
__device__ __forceinline__ void load16(const void* g, void* l) {
  __builtin_amdgcn_global_load_lds(
      (const __attribute__((address_space(1))) u32*)g,
      (__attribute__((address_space(3))) u32*)l, 16, 0, 0);
}

// ---------------------------------------------------------------------------
// Convert one 128k x 64n tile: fp32 [K][N] -> bf16 [N][K].
// All 8 float4 loads issued before any use (sched_barrier pins the cluster).
// Write phase: each store covers 4 FULL 256B row segments.
// ---------------------------------------------------------------------------
__device__ __forceinline__ void conv_tile(
    const float* __restrict__ src, u16* __restrict__ dst,
    int K, int N, int k0, int n0, char* smem, int tid, int lane, int wid)
{
  u16* lt = (u16*)smem;             // [64 n][CLD k]
  const int rr = tid >> 4;          // k sub-row 0..15
  const int cc = (tid & 15) << 2;   // n 0..60

  const float* s0 = src + (size_t)(k0 + rr) * N + n0 + cc;
  float4 v[8];
#pragma unroll
  for (int j = 0; j < 8; ++j) v[j] = *(const float4*)(s0 + (size_t)j * 16 * N);
  __builtin_amdgcn_sched_barrier(0);   // keep all 8 loads in flight

#pragma unroll
  for (int j = 0; j < 8; ++j) {
    const int k = j * 16 + rr;
    lt[(cc + 0) * CLD + k] = f2bf(v[j].x); lt[(cc + 1) * CLD + k] = f2bf(v[j].y);
    lt[(cc + 2) * CLD + k] = f2bf(v[j].z); lt[(cc + 3) * CLD + k] = f2bf(v[j].w);
  }
  __syncthreads();

  const int l15 = lane & 15;        // 16B chunk within row (k)
  const int r4  = lane >> 4;        // row within 4-row group
#pragma unroll
  for (int s = 0; s < 4; ++s) {
    const int r = wid * 16 + s * 4 + r4;   // n row 0..63
    u16x8 vv;
#pragma unroll
    for (int d = 0; d < 8; ++d) vv[d] = lt[r * CLD + l15 * 8 + d];
    *(u16x8*)(dst + (size_t)(n0 + r) * K + k0 + l15 * 8) = vv;
  }
}

// ---------------------------------------------------------------------------
// Kernel 1: router (blocks [0,256)) + w1 convert (blocks [256, 256+2304)).
// Router first in dispatch order so scatter's inputs finish early.
// ---------------------------------------------------------------------------
__global__ __launch_bounds__(256, 4) void conv1_router_kernel(
    const float* __restrict__ w1, u16* __restrict__ w1t,
    const float* __restrict__ x, const float* __restrict__ rw,
    u16* __restrict__ xb, int* __restrict__ counts,
    int* __restrict__ ti, int* __restrict__ tpos, float* __restrict__ tg)
{
  __shared__ __align__(16) char smem[64 * CLD * 2];   // 16640 B
  const int tid  = threadIdx.x;
  const int lane = tid & 63;
  const int wid  = tid >> 6;

  if (blockIdx.x >= NB_ROUTER) {
    const int cid = blockIdx.x - NB_ROUTER;
    const int z   = cid / 288;
    const int rem = cid % 288;
    conv_tile(w1 + (size_t)z * HD * FF, w1t + (size_t)z * FF * HD,
              HD, FF, (rem / 48) * 128, (rem % 48) * 64, smem, tid, lane, wid);
  } else {
    // ---------------- router path (no LDS) ----------------
    const int t = blockIdx.x * 4 + wid;
    const float* xrow = x + (size_t)t * HD;
    u16* xbrow = xb + (size_t)t * HD;

    float acc[NE] = {};
#pragma unroll
    for (int j = 0; j < 12; ++j) {
      const int h = lane + j * 64;
      const float xv = xrow[h];
      xbrow[h] = f2bf(xv);
      const float4 r0 = *(const float4*)(rw + h * 8);
      const float4 r1 = *(const float4*)(rw + h * 8 + 4);
      acc[0] += xv * r0.x; acc[1] += xv * r0.y;
      acc[2] += xv * r0.z; acc[3] += xv * r0.w;
      acc[4] += xv * r1.x; acc[5] += xv * r1.y;
      acc[6] += xv * r1.z; acc[7] += xv * r1.w;
    }
#pragma unroll
    for (int e = 0; e < NE; ++e) {
      float v = acc[e];
#pragma unroll
      for (int off = 32; off; off >>= 1) v += __shfl_down(v, off, 64);
      acc[e] = v;
    }

    if (lane == 0) {
      float v0 = -1e30f, v1 = -1e30f; int i0 = 0, i1 = 0;
#pragma unroll
      for (int e = 0; e < NE; ++e) {
        const float p = acc[e];
        if (p > v0) { v1 = v0; i1 = i0; v0 = p; i0 = e; }
        else if (p > v1) { v1 = p; i1 = e; }
      }
      const float e1 = expf(v1 - v0);
      const float g0 = 1.0f / (1.0f + e1);
      const float g1 = e1 / (1.0f + e1);
      const int p0 = atomicAdd(&counts[i0], 1);
      const int p1 = atomicAdd(&counts[i1], 1);
      ti[2 * t] = i0;  ti[2 * t + 1] = i1;
      tpos[2 * t] = p0; tpos[2 * t + 1] = p1;
      tg[2 * t] = g0;  tg[2 * t + 1] = g1;
    }
  }
}

// ---------------------------------------------------------------------------
// Router stage B: prefix-sum counts -> seg, scatter slots.
// ---------------------------------------------------------------------------
__global__ __launch_bounds__(1024) void router_scatter(
    const int* __restrict__ counts, const int* __restrict__ ti,
    const int* __restrict__ tpos, const float* __restrict__ tg,
    int* __restrict__ tos, float* __restrict__ gos, int* __restrict__ seg)
{
  __shared__ int offs[NE];
  const int t = threadIdx.x;
  if (t == 0) {
    int o = 0;
    for (int e = 0; e < NE; ++e) {
      offs[e] = o; seg[e] = o; seg[NE + e] = counts[e]; o += counts[e];
    }
  }
  __syncthreads();
  const int i0 = ti[2 * t], i1 = ti[2 * t + 1];
  const int s0 = offs[i0] + tpos[2 * t];
  const int s1 = offs[i1] + tpos[2 * t + 1];
  tos[s0] = t; gos[s0] = tg[2 * t];
  tos[s1] = t; gos[s1] = tg[2 * t + 1];
}

// ---------------------------------------------------------------------------
// Kernel 3: ffn1 (MFMA) fused with w2 convert (memory) — independent work,
// interleaved 4:3 per 7-block group for co-residency. Single-buffered LDS
// (25 KB union -> 6 blocks/CU).
//
// FFN1 core: 128m x 64n tile, BK=64, 4 waves (2x2 over 64x32 each, acc 4x2).
// global_load_lds staging, XOR-swizzled unpadded LDS
// (physical 16B chunk = logical ^ (row&7)).
// ---------------------------------------------------------------------------
__global__ __launch_bounds__(256) void ffn1_conv2_kernel(
    const u16* __restrict__ xb, const u16* __restrict__ w1t,
    const int* __restrict__ tos, const int* __restrict__ seg,
    u16* __restrict__ hbuf,
    const float* __restrict__ w2, u16* __restrict__ w2t)
{
  __shared__ __align__(16) char smem[25088];   // max(ffn1 25088, conv 16640)
  const int tid  = threadIdx.x;
  const int lane = tid & 63;
  const int wid  = tid >> 6;

  const int g  = blockIdx.x / 7;
  const int r7 = blockIdx.x % 7;

  if (r7 >= 4) {
    // ---------------- w2 convert path ----------------
    const int cid = g * 3 + (r7 - 4);
    const int z   = cid / 288;
    const int rem = cid % 288;
    conv_tile(w2 + (size_t)z * FF * HD, w2t + (size_t)z * HD * FF,
              FF, HD, (rem % 24) * 128, (rem / 24) * 64, smem, tid, lane, wid);
    return;
  }

  // ---------------- ffn1 path ----------------
  const int fid = g * 4 + r7;
  const int e   = fid / 384;
  const int m0  = ((fid / 48) % 8) * 128;
  const int n0  = (fid % 48) * 64;
  const int cnt = seg[NE + e];
  if (m0 >= cnt) return;
  const int start = seg[e];

  u16* As   = (u16*)smem;              // 128*64*2 = 16384
  u16* Bs   = (u16*)(smem + 16384);    // 64*64*2  =  8192
  int* toks = (int*)(smem + 24576);    // 128*4    =   512

  if (tid < 128) toks[tid] = tos[start + min(m0 + tid, cnt - 1)];
  __syncthreads();

  const int rsub = lane >> 3;           // 0..7
  const int c8   = (lane & 7) ^ rsub;   // logical 16B chunk

  const u16* ag[4]; u16* al[4];
#pragma unroll
  for (int i = 0; i < 4; ++i) {
    const int rb = wid * 8 + i * 32;
    ag[i] = xb + (size_t)toks[rb + rsub] * HD + c8 * 8;
    al[i] = As + rb * 64;
  }
  const u16* bg[2]; u16* bl[2];
#pragma unroll
  for (int i = 0; i < 2; ++i) {
    const int rb = wid * 8 + i * 32;
    bg[i] = w1t + ((size_t)e * FF + n0 + rb + rsub) * HD + c8 * 8;
    bl[i] = Bs + rb * 64;
  }

  const int wm  = (wid >> 1) << 6;      // 0 / 64
  const int wn  = (wid & 1) << 5;       // 0 / 32
  const int q   = lane >> 4;
  const int r16 = lane & 15;

  f32x4 acc[4][2] = {};

  for (int k0 = 0; k0 < HD; k0 += BK) {
#pragma unroll
    for (int i = 0; i < 4; ++i) load16(ag[i] + k0, al[i]);
#pragma unroll
    for (int i = 0; i < 2; ++i) load16(bg[i] + k0, bl[i]);
    __syncthreads();
#pragma unroll
    for (int s = 0; s < 2; ++s) {
      const int pa = ((s << 2) + q) ^ (r16 & 7);
      bf16x8 af[4], bf[2];
#pragma unroll
      for (int t = 0; t < 4; ++t)
        af[t] = *(const bf16x8*)(&As[(wm + t * 16 + r16) * 64 + pa * 8]);
#pragma unroll
      for (int t = 0; t < 2; ++t)
        bf[t] = *(const bf16x8*)(&Bs[(wn + t * 16 + r16) * 64 + pa * 8]);
#pragma unroll
      for (int t = 0; t < 4; ++t)
#pragma unroll
        for (int c = 0; c < 2; ++c)
          acc[t][c] = __builtin_amdgcn_mfma_f32_16x16x32_bf16(af[t], bf[c], acc[t][c], 0, 0, 0);
    }
    __syncthreads();
  }

#pragma unroll
  for (int t = 0; t < 4; ++t) {
    const int mbase = m0 + wm + t * 16 + q * 4;
#pragma unroll
    for (int i = 0; i < 4; ++i) {
      if (mbase + i < cnt) {
        u16* drow = hbuf + (size_t)(start + mbase + i) * FF + n0 + wn;
#pragma unroll
        for (int c = 0; c < 2; ++c) {
          float v = acc[t][c][i];
          v = 0.5f * v * (1.0f + erff(v * 0.70710678118f));
          drow[c * 16 + r16] = f2bf(v);
        }
      }
    }
  }
}

// FFN2: out += gate * (h @ w2t[e]), K-split x4, atomic fp32 accumulate.
#define KSPLIT 4
#define KSEG   (FF / KSPLIT)   // 768

__global__ __launch_bounds__(256) void ffn2_kernel(
    const u16* __restrict__ hbuf, const u16* __restrict__ w2t,
    const int* __restrict__ tos, const float* __restrict__ gos,
    const int* __restrict__ seg, float* __restrict__ out)
{
  const int ez  = blockIdx.z;
  const int e   = ez >> 2;
  const int ks  = ez & 3;
  const int cnt = seg[NE + e];
  const int m0  = blockIdx.y * 128;
  if (m0 >= cnt) return;
  const int start = seg[e];
  const int n0    = blockIdx.x * 64;
  const int kbase = ks * KSEG;

  __shared__ __align__(16) u16 As[128 * 64];
  __shared__ __align__(16) u16 Bs[64 * 64];
  __shared__ int   toks[128];
  __shared__ float gates[128];

  const int tid = threadIdx.x;
  if (tid < 128) {
    const int idx = start + min(m0 + tid, cnt - 1);
    toks[tid]  = tos[idx];
    gates[tid] = gos[idx];
  }
  __syncthreads();

  const int lane = tid & 63;
  const int wid  = tid >> 6;
  const int rsub = lane >> 3;
  const int c8   = (lane & 7) ^ rsub;

  const u16* ag[4]; u16* al[4];
#pragma unroll
  for (int i = 0; i < 4; ++i) {
    const int rb = wid * 8 + i * 32;
    ag[i] = hbuf + (size_t)(start + min(m0 + rb + rsub, cnt - 1)) * FF + kbase + c8 * 8;
    al[i] = As + rb * 64;
  }
  const u16* bg[2]; u16* bl[2];
#pragma unroll
  for (int i = 0; i < 2; ++i) {
    const int rb = wid * 8 + i * 32;
    bg[i] = w2t + ((size_t)e * HD + n0 + rb + rsub) * FF + kbase + c8 * 8;
    bl[i] = Bs + rb * 64;
  }

  const int wm  = (wid >> 1) << 6;
  const int wn  = (wid & 1) << 5;
  const int q   = lane >> 4;
  const int r16 = lane & 15;

  f32x4 acc[4][2] = {};

  for (int k0 = 0; k0 < KSEG; k0 += BK) {
#pragma unroll
    for (int i = 0; i < 4; ++i) load16(ag[i] + k0, al[i]);
#pragma unroll
    for (int i = 0; i < 2; ++i) load16(bg[i] + k0, bl[i]);
    __syncthreads();
#pragma unroll
    for (int s = 0; s < 2; ++s) {
      const int pa = ((s << 2) + q) ^ (r16 & 7);
      bf16x8 af[4], bf[2];
#pragma unroll
      for (int t = 0; t < 4; ++t)
        af[t] = *(const bf16x8*)(&As[(wm + t * 16 + r16) * 64 + pa * 8]);
#pragma unroll
      for (int t = 0; t < 2; ++t)
        bf[t] = *(const bf16x8*)(&Bs[(wn + t * 16 + r16) * 64 + pa * 8]);
#pragma unroll
      for (int t = 0; t < 4; ++t)
#pragma unroll
        for (int c = 0; c < 2; ++c)
          acc[t][c] = __builtin_amdgcn_mfma_f32_16x16x32_bf16(af[t], bf[c], acc[t][c], 0, 0, 0);
    }
    __syncthreads();
  }

#pragma unroll
  for (int t = 0; t < 4; ++t) {
    const int mbase = wm + t * 16 + q * 4;
#pragma unroll
    for (int i = 0; i < 4; ++i) {
      const int mloc = mbase + i;
      if (m0 + mloc < cnt) {
        const int tok  = toks[mloc];
        const float g  = gates[mloc];
        float* drow = out + (size_t)tok * HD + n0 + wn;
#pragma unroll
        for (int c = 0; c < 2; ++c) {
          atomicAdd(drow + c * 16 + r16, g * acc[t][c][i]);
        }
      }
    }
  }
}

// ---------------------------------------------------------------------------
extern "C" void kernel_launch(void* const* d_in, const int* in_sizes, int n_in,
                              void* d_out, int out_size, void* d_ws, size_t ws_size,
                              hipStream_t stream) {
  const float* x  = (const float*)d_in[0];
  const float* rw = (const float*)d_in[1];
  const float* w1 = (const float*)d_in[2];
  const float* w2 = (const float*)d_in[3];
  float* out = (float*)d_out;

  char* ws = (char*)d_ws;
  const size_t o_xb    = 0;
  const size_t o_hbuf  = o_xb + (size_t)NTOK * HD * 2;
  const size_t o_tos   = o_hbuf + (size_t)NSLOT * FF * 2;
  const size_t o_gos   = o_tos + (size_t)NSLOT * 4;
  const size_t o_seg   = o_gos + (size_t)NSLOT * 4;
  const size_t o_cnt   = o_seg + 64 * 4;
  const size_t o_ti    = o_cnt + NE * 4;
  const size_t o_tpos  = o_ti + (size_t)NSLOT * 4;
  const size_t o_tg    = o_tpos + (size_t)NSLOT * 4;
  const size_t o_w1t   = (o_tg + (size_t)NSLOT * 4 + 255) & ~(size_t)255;
  const size_t o_w2t   = o_w1t + (size_t)NE * HD * FF * 2;
  u16*   xb    = (u16*)(ws + o_xb);
  u16*   hbuf  = (u16*)(ws + o_hbuf);
  int*   tos   = (int*)(ws + o_tos);
  float* gos   = (float*)(ws + o_gos);
  int*   seg   = (int*)(ws + o_seg);
  int*   cnts  = (int*)(ws + o_cnt);
  int*   ti    = (int*)(ws + o_ti);
  int*   tpos  = (int*)(ws + o_tpos);
  float* tg    = (float*)(ws + o_tg);
  u16*   w1t   = (u16*)(ws + o_w1t);
  u16*   w2t   = (u16*)(ws + o_w2t);

  hipMemsetAsync(d_out, 0, (size_t)NTOK * HD * sizeof(float), stream);
  hipMemsetAsync(cnts, 0, NE * sizeof(int), stream);
  hipLaunchKernelGGL(conv1_router_kernel, dim3(NB_ROUTER + NB_CONV1), dim3(256), 0, stream,
                     w1, w1t, x, rw, xb, cnts, ti, tpos, tg);
  hipLaunchKernelGGL(router_scatter, dim3(1), dim3(1024), 0, stream,
                     cnts, ti, tpos, tg, tos, gos, seg);
  hipLaunchKernelGGL(ffn1_conv2_kernel, dim3((NB_FFN1 + NB_CONV2)), dim3(256), 0, stream,
                     xb, w1t, tos, seg, hbuf, w2, w2t);
  hipLaunchKernelGGL(ffn2_kernel, dim3(HD / 64, NTOK / 128, NE * KSPLIT), dim3(256), 0, stream,
                     hbuf, w2t, tos, gos, seg, out);
}